// Round 4
// baseline (1129.654 us; speedup 1.0000x reference)
//
#include <hip/hip_runtime.h>
#include <stdint.h>

typedef unsigned short u16;
typedef __attribute__((ext_vector_type(8))) short short8;
typedef __attribute__((ext_vector_type(4))) float f32x4;

#define DEVI __device__ __forceinline__

// problem constants
#define BB   256
#define LL   100
#define CC   55
#define DD   512
#define HH   8
#define DKK  64
#define MM   (BB * LL)   // 25600 tokens
#define KEMB 192         // 3 * 64 (c padded 55->64)
#define NSEG 17

DEVI float bf2f(u16 s) { union { unsigned int u; float f; } x; x.u = ((unsigned int)s) << 16; return x.f; }
DEVI u16 f2bf(float f) {
  union { float f; unsigned int u; } x; x.f = f;
  unsigned int u = x.u;
  return (u16)((u + 0x7FFFu + ((u >> 16) & 1u)) >> 16);
}

DEVI void async_lds16(const u16* gp, u16* lp) {
  __builtin_amdgcn_global_load_lds((const __attribute__((address_space(1))) void*)gp,
                                   (__attribute__((address_space(3))) void*)lp, 16, 0, 0);
}

// ---------------- dtype detect + canonicalize ----------------
__global__ void detect_dtype(const u16* __restrict__ x, int* __restrict__ flag) {
  __shared__ int cnt[256];
  int tid = threadIdx.x;
  u16 u = x[2 * tid];
  int e = (u >> 7) & 0xFF;
  cnt[tid] = (e >= 0x5F && e <= 0x90) ? 1 : 0;   // |v| in [2^-32, 2^17]
  __syncthreads();
  for (int s = 128; s > 0; s >>= 1) { if (tid < s) cnt[tid] += cnt[tid + s]; __syncthreads(); }
  if (tid == 0) *flag = (cnt[0] >= 160) ? 0 : 1;
}

struct Segs { const void* src[NSEG]; int off[NSEG + 1]; };

__global__ void convert_all(Segs s, const int* __restrict__ flag, u16* __restrict__ dst) {
  int i = blockIdx.x * 256 + threadIdx.x;
  if (i >= s.off[NSEG]) return;
  int sidx = 0;
#pragma unroll
  for (int k = 1; k < NSEG; k++) if (i >= s.off[k]) sidx = k;
  int j = i - s.off[sidx];
  u16 v;
  if (*flag) v = f2bf(((const float*)s.src[sidx])[j]);
  else       v = ((const u16*)s.src[sidx])[j];
  dst[i] = v;
}

// ---------------- repack kernels (embedding conv -> GEMM) ----------------
__global__ void repack_w(const u16* __restrict__ tokw, u16* __restrict__ Wg) {
  int idx = blockIdx.x * 256 + threadIdx.x;   // 512*192
  if (idx >= 512 * KEMB) return;
  int d = idx / KEMB, j = idx % KEMB, k = j >> 6, c = j & 63;
  Wg[idx] = (c < CC) ? tokw[d * (CC * 3) + c * 3 + k] : (u16)0;
}

__global__ void repack_x(const u16* __restrict__ x, u16* __restrict__ Xg) {
  int idx = blockIdx.x * 256 + threadIdx.x;   // 25600*192
  if (idx >= MM * KEMB) return;
  int m = idx / KEMB, j = idx % KEMB, k = j >> 6, c = j & 63;
  int b = m / LL, l = m % LL;
  int l2 = l + k - 1; l2 = (l2 + LL) % LL;    // circular pad
  Xg[idx] = (c < CC) ? x[(size_t)(b * LL + l2) * CC + c] : (u16)0;
}

// ---------------- bf16 MFMA GEMM: out = A[M,K] @ W[N,K]^T (+epilogue) ----------------
// BM=128, BK=64, 256 threads = 4 waves as 2x2.
// QKV: grid.y spans 3 concatenated weight sets (block-uniform sel by n0>>9).
// Epilogue: master fp32 R/W direct in C-fragment layout (quad-coalesced dwords);
// bf16 output via ONE LDS transpose (pad +16 -> conflict-free quads) + bf16x8 stores.
// DIRECT (proj): scalar masked stores straight from fragments.
struct GemmW { const u16* W[3]; const u16* bias[3]; void* out[3]; };

template<int BN, int TAG, bool QKV, bool DIRECT>
__global__ __launch_bounds__(256)
void gemm_bt(const u16* __restrict__ A, int K, GemmW w,
             const u16* __restrict__ pe,     // if non-null: add pe[(m%100)*512+col]
             float* __restrict__ master,     // if non-null: (addm? +=) write fp32 master [M,512]
             int addm, int dogelu,
             int ldo, int nvalid,
             const int* __restrict__ dtf)    // DIRECT only: *dtf==1 -> fp32 store
{
  constexpr int BM = 128, BK = 64;
  constexpr int WN = BN / 2, NT = WN / 16;
  constexpr int LSW = BN + 16;                        // row stride 8 dw mod 32 -> quad spread
  constexpr int STAGE_U16 = (BM + BN) * BK;
  constexpr int EPI_U16 = DIRECT ? 0 : BM * LSW;
  constexpr int SM_U16 = STAGE_U16 > EPI_U16 ? STAGE_U16 : EPI_U16;
  __shared__ alignas(16) u16 smem[SM_U16];
  u16* As = smem;
  u16* Bs = smem + BM * BK;

  const int tid = threadIdx.x;
  const int lane = tid & 63;
  const int wv = __builtin_amdgcn_readfirstlane(tid >> 6);
  const int wm = wv & 1, wn = wv >> 1;
  const int l15 = lane & 15, qd = lane >> 4;
  const int m0 = blockIdx.x * BM;
  int n0 = blockIdx.y * BN;
  int sel = 0, n0l = n0;
  if (QKV) { sel = n0 >> 9; n0l = n0 & 511; }
  const u16* W = w.W[sel];
  const u16* bias = w.bias[sel];
  void* outp = w.out[sel];

  const f32x4 zf = {0.f, 0.f, 0.f, 0.f};
  f32x4 acc[4][NT];
#pragma unroll
  for (int i = 0; i < 4; i++)
#pragma unroll
    for (int j = 0; j < NT; j++) acc[i][j] = zf;

  for (int k0 = 0; k0 < K; k0 += BK) {
    __syncthreads();
#pragma unroll
    for (int i = 0; i < 4; i++) {                     // A: 128x64 = 16KB, 1024 chunks
      int base = i * 256 + wv * 64;
      int idx = base + lane;
      int row = idx >> 3, c8 = (idx & 7) * 8;
      async_lds16(A + (size_t)(m0 + row) * K + k0 + c8, As + base * 8);
    }
#pragma unroll
    for (int i = 0; i < BN / 32; i++) {               // B rows, clamped tail
      int base = i * 256 + wv * 64;
      int idx = base + lane;
      int row = idx >> 3, c8 = (idx & 7) * 8;
      int gr = n0l + row; if (gr >= nvalid) gr = nvalid - 1;
      async_lds16(W + (size_t)gr * K + k0 + c8, Bs + base * 8);
    }
    __syncthreads();

#pragma unroll
    for (int ks = 0; ks < 2; ks++) {
      short8 af[4], bfr[NT];
#pragma unroll
      for (int mi = 0; mi < 4; mi++)
        af[mi] = *(const short8*)&As[(wm * 64 + mi * 16 + l15) * BK + ks * 32 + qd * 8];
#pragma unroll
      for (int ni = 0; ni < NT; ni++)
        bfr[ni] = *(const short8*)&Bs[(wn * WN + ni * 16 + l15) * BK + ks * 32 + qd * 8];
#pragma unroll
      for (int mi = 0; mi < 4; mi++)
#pragma unroll
        for (int ni = 0; ni < NT; ni++)
          acc[mi][ni] = __builtin_amdgcn_mfma_f32_16x16x32_bf16(af[mi], bfr[ni], acc[mi][ni], 0, 0, 0);
    }
  }

  // C/D layout: col=lane&15, row=(lane>>4)*4+reg [verified m89/m91]
  if (DIRECT) {
    const int sf = (dtf != nullptr) ? *dtf : 0;
#pragma unroll
    for (int mi = 0; mi < 4; mi++)
#pragma unroll
      for (int ni = 0; ni < NT; ni++) {
        int gcol = n0l + wn * WN + ni * 16 + l15;
        float bv = (bias && gcol < nvalid) ? bf2f(bias[gcol]) : 0.f;
#pragma unroll
        for (int r = 0; r < 4; r++) {
          int grow = m0 + wm * 64 + mi * 16 + qd * 4 + r;
          if (gcol < nvalid) {
            float v = acc[mi][ni][r] + bv;
            if (sf) ((float*)outp)[(size_t)grow * ldo + gcol] = v;
            else    ((u16*)outp)[(size_t)grow * ldo + gcol] = f2bf(v);
          }
        }
      }
    return;
  }

  __syncthreads();                                    // staging reads done; reuse smem
  u16* Ls = smem;
#pragma unroll
  for (int mi = 0; mi < 4; mi++) {
    const int lr = wm * 64 + mi * 16 + qd * 4;        // local row base for this mi
    float mv[NT][4];
    if (!QKV && master) {                             // batch 16 dword loads (quad-coalesced)
#pragma unroll
      for (int ni = 0; ni < NT; ni++) {
        int col = n0l + wn * WN + ni * 16 + l15;
#pragma unroll
        for (int r = 0; r < 4; r++)
          mv[ni][r] = master[(size_t)(m0 + lr + r) * DD + col];
      }
    }
    float pv[NT][4];
    if (!QKV && pe) {
#pragma unroll
      for (int ni = 0; ni < NT; ni++) {
        int col = n0l + wn * WN + ni * 16 + l15;
#pragma unroll
        for (int r = 0; r < 4; r++)
          pv[ni][r] = bf2f(pe[((m0 + lr + r) % LL) * DD + col]);
      }
    }
#pragma unroll
    for (int ni = 0; ni < NT; ni++) {
      const int lc = wn * WN + ni * 16 + l15;
      float bv = bias ? bf2f(bias[n0l + lc]) : 0.f;
#pragma unroll
      for (int r = 0; r < 4; r++) {
        float v = acc[mi][ni][r] + bv;
        if (!QKV && pe) v += pv[ni][r];
        if (!QKV && master) {
          if (addm) v += mv[ni][r];
          master[(size_t)(m0 + lr + r) * DD + n0l + lc] = v;
        }
        if (!QKV && dogelu) v = 0.5f * v * (1.f + erff(v * 0.70710678118654752f));
        Ls[(lr + r) * LSW + lc] = f2bf(v);
      }
    }
  }
  __syncthreads();
  {                                                   // wide bf16x8 stores
    const int tr = tid >> 1;
    const int tc = (tid & 1) * (BN / 2);
    u16* op = (u16*)outp + (size_t)(m0 + tr) * ldo + n0l + tc;
#pragma unroll
    for (int c = 0; c < BN / 2; c += 8)
      *(short8*)&op[c] = *(const short8*)&Ls[tr * LSW + tc + c];
  }
}

// ---------------- fused attention: one block per (b,h) ----------------
__global__ __launch_bounds__(256)
void attn(const u16* __restrict__ qg, const u16* __restrict__ kg,
          const u16* __restrict__ vg, u16* __restrict__ og)
{
  constexpr int LP = 128;
  __shared__ alignas(16) u16 Ks[LP * DKK];   // 16 KB
  __shared__ alignas(16) u16 Vt[DKK * LP];   // 16 KB  V transposed [d][j]
  __shared__ alignas(16) u16 Ps[LP * LP];    // 32 KB  probs; reused for O staging

  const int bh = blockIdx.x;
  const int b = bh >> 3, h = bh & 7;
  const size_t base = (size_t)b * LL * DD + (size_t)h * DKK;
  const int tid = threadIdx.x, lane = tid & 63, wv = tid >> 6;
  const int l15 = lane & 15, qd = lane >> 4;
  const short8 z8 = {0, 0, 0, 0, 0, 0, 0, 0};

  for (int i = tid; i < LP * 8; i += 256) {            // K rows, zero-padded
    int row = i >> 3, e8 = (i & 7) * 8;
    short8 val = z8;
    if (row < LL) val = *(const short8*)(kg + base + (size_t)row * DD + e8);
    *(short8*)&Ks[row * DKK + e8] = val;
  }
  for (int i = tid; i < LP * 8; i += 256) {            // V transposed
    int j = i & 127, d0 = (i >> 7) * 8;
    short8 val = z8;
    if (j < LL) val = *(const short8*)(vg + base + (size_t)j * DD + d0);
#pragma unroll
    for (int u = 0; u < 8; u++) Vt[(d0 + u) * LP + j] = (u16)val[u];
  }
  __syncthreads();

  const f32x4 zf = {0.f, 0.f, 0.f, 0.f};
  f32x4 sc[2][8];
#pragma unroll
  for (int it = 0; it < 2; it++)
#pragma unroll
    for (int jt = 0; jt < 8; jt++) sc[it][jt] = zf;

  short8 af[2][2];
#pragma unroll
  for (int it = 0; it < 2; it++) {
    int row = (2 * wv + it) * 16 + l15;
#pragma unroll
    for (int ks = 0; ks < 2; ks++) {
      short8 val = z8;
      if (row < LL) val = *(const short8*)(qg + base + (size_t)row * DD + ks * 32 + qd * 8);
      af[it][ks] = val;
    }
  }
#pragma unroll
  for (int jt = 0; jt < 8; jt++) {
    short8 b0 = *(const short8*)&Ks[(jt * 16 + l15) * DKK + qd * 8];
    short8 b1 = *(const short8*)&Ks[(jt * 16 + l15) * DKK + 32 + qd * 8];
#pragma unroll
    for (int it = 0; it < 2; it++) {
      sc[it][jt] = __builtin_amdgcn_mfma_f32_16x16x32_bf16(af[it][0], b0, sc[it][jt], 0, 0, 0);
      sc[it][jt] = __builtin_amdgcn_mfma_f32_16x16x32_bf16(af[it][1], b1, sc[it][jt], 0, 0, 0);
    }
  }

  constexpr float scale = 0.125f;   // 1/sqrt(64)
#pragma unroll
  for (int it = 0; it < 2; it++) {
    int rb = (2 * wv + it) * 16 + qd * 4;
#pragma unroll
    for (int r = 0; r < 4; r++) {
      float vals[8];
      float mx = -1e30f;
#pragma unroll
      for (int jt = 0; jt < 8; jt++) {
        int col = jt * 16 + l15;
        float vv = sc[it][jt][r] * scale;
        if (col >= LL) vv = -1e30f;
        vals[jt] = vv;
        mx = fmaxf(mx, vv);
      }
#pragma unroll
      for (int off = 1; off < 16; off <<= 1) mx = fmaxf(mx, __shfl_xor(mx, off, 64));
      float s = 0.f;
#pragma unroll
      for (int jt = 0; jt < 8; jt++) { float p = __expf(vals[jt] - mx); vals[jt] = p; s += p; }
#pragma unroll
      for (int off = 1; off < 16; off <<= 1) s += __shfl_xor(s, off, 64);
      float inv = 1.f / s;
      int rowp = rb + r;
#pragma unroll
      for (int jt = 0; jt < 8; jt++) Ps[rowp * LP + jt * 16 + l15] = f2bf(vals[jt] * inv);
    }
  }
  __syncthreads();

  f32x4 oc[2][4];
#pragma unroll
  for (int it = 0; it < 2; it++)
#pragma unroll
    for (int dt = 0; dt < 4; dt++) oc[it][dt] = zf;
#pragma unroll
  for (int ks = 0; ks < 4; ks++) {
    short8 ap[2];
#pragma unroll
    for (int it = 0; it < 2; it++)
      ap[it] = *(const short8*)&Ps[((2 * wv + it) * 16 + l15) * LP + ks * 32 + qd * 8];
#pragma unroll
    for (int dt = 0; dt < 4; dt++) {
      short8 bv = *(const short8*)&Vt[(dt * 16 + l15) * LP + ks * 32 + qd * 8];
#pragma unroll
      for (int it = 0; it < 2; it++)
        oc[it][dt] = __builtin_amdgcn_mfma_f32_16x16x32_bf16(ap[it], bv, oc[it][dt], 0, 0, 0);
    }
  }

  // O staging -> vectorized store (reuse Ps as [128][64] bf16)
  __syncthreads();
  u16* Os = Ps;
#pragma unroll
  for (int it = 0; it < 2; it++) {
    int rb = (2 * wv + it) * 16 + qd * 4;
#pragma unroll
    for (int dt = 0; dt < 4; dt++)
#pragma unroll
      for (int r = 0; r < 4; r++)
        Os[(rb + r) * DKK + dt * 16 + l15] = f2bf(oc[it][dt][r]);
  }
  __syncthreads();
  {
    int row = tid >> 1, c0 = (tid & 1) * 32;
    if (row < LL) {
      u16* op = og + base + (size_t)row * DD + c0;
#pragma unroll
      for (int c = 0; c < 32; c += 8)
        *(short8*)&op[c] = *(const short8*)&Os[row * DKK + c0 + c];
    }
  }
}

// ---------------- launch ----------------
extern "C" void kernel_launch(void* const* d_in, const int* in_sizes, int n_in,
                              void* d_out, int out_size, void* d_ws, size_t ws_size,
                              hipStream_t stream)
{
  (void)in_sizes; (void)n_in; (void)out_size; (void)ws_size;

  char* ws = (char*)d_ws;
  size_t off = 0;
  auto alloc = [&](size_t bytes) { char* p = ws + off; off += (bytes + 255) & ~(size_t)255; return p; };
  int* dflag = (int*)alloc(256);
  static const int seg_sizes[NSEG] = {
    MM * CC, DD * CC * 3, LL * DD,
    3 * DD * DD, 3 * DD, 3 * DD * DD, 3 * DD, 3 * DD * DD, 3 * DD,
    3 * DD * DD, 3 * DD, 3 * 64 * DD, 3 * 64, 3 * DD * 64, 3 * DD,
    CC * DD, CC
  };
  static const int seg_input[NSEG] = {0, 1, 2, 3, 4, 5, 6, 7, 8, 11, 12, 13, 14, 15, 16, 17, 18};
  int total = 0, segoff[NSEG + 1];
  for (int i = 0; i < NSEG; i++) { segoff[i] = total; total += seg_sizes[i]; }
  segoff[NSEG] = total;
  u16* canon = (u16*)alloc((size_t)total * 2);

  float* h32 = (float*)alloc((size_t)MM * DD * 4);
  u16* hbf = (u16*)alloc((size_t)MM * DD * 2);
  u16* qb  = (u16*)alloc((size_t)MM * DD * 2);
  u16* kb  = (u16*)alloc((size_t)MM * DD * 2);
  u16* vb  = (u16*)alloc((size_t)MM * DD * 2);
  u16* ob  = (u16*)alloc((size_t)MM * DD * 2);
  u16* yb  = (u16*)alloc((size_t)MM * 64 * 2);
  u16* Wg  = (u16*)alloc((size_t)512 * KEMB * 2);
  u16* Xg  = qb;   // alias: Xg dead before qb first written (stream-serialized)

  const u16* xc  = canon + segoff[0];
  const u16* twc = canon + segoff[1];
  const u16* pec = canon + segoff[2];
  const u16* Wqc = canon + segoff[3];  const u16* bqc = canon + segoff[4];
  const u16* Wkc = canon + segoff[5];  const u16* bkc = canon + segoff[6];
  const u16* Wvc = canon + segoff[7];  const u16* bvc = canon + segoff[8];
  const u16* Woc = canon + segoff[9];  const u16* boc = canon + segoff[10];
  const u16* W1c = canon + segoff[11]; const u16* b1c = canon + segoff[12];
  const u16* W2c = canon + segoff[13]; const u16* b2c = canon + segoff[14];
  const u16* pwc = canon + segoff[15]; const u16* pbc = canon + segoff[16];

  Segs sg;
  for (int i = 0; i < NSEG; i++) { sg.src[i] = d_in[seg_input[i]]; sg.off[i] = segoff[i]; }
  sg.off[NSEG] = total;

  dim3 blk(256);
  detect_dtype<<<dim3(1), blk, 0, stream>>>((const u16*)d_in[0], dflag);
  convert_all<<<dim3((total + 255) / 256), blk, 0, stream>>>(sg, dflag, canon);
  repack_w<<<dim3((512 * KEMB + 255) / 256), blk, 0, stream>>>(twc, Wg);
  repack_x<<<dim3((MM * KEMB + 255) / 256), blk, 0, stream>>>(xc, Xg);

  auto W1of = [&](const u16* p) { GemmW g{}; g.W[0] = g.W[1] = g.W[2] = p; return g; };

  // embedding GEMM: h = Xg @ Wg^T + pe -> h32 (write), hbf   [TAG 0]
  { GemmW g = W1of(Wg); g.out[0] = hbf;
    gemm_bt<128, 0, false, false><<<dim3(MM / 128, 4), blk, 0, stream>>>(Xg, KEMB, g, pec, h32, 0, 0, DD, DD, nullptr); }

  for (int l = 0; l < 3; l++) {
    const u16* Wq_l = Wqc + (size_t)l * DD * DD; const u16* bq_l = bqc + l * DD;
    const u16* Wk_l = Wkc + (size_t)l * DD * DD; const u16* bk_l = bkc + l * DD;
    const u16* Wv_l = Wvc + (size_t)l * DD * DD; const u16* bv_l = bvc + l * DD;
    const u16* Wo_l = Woc + (size_t)l * DD * DD; const u16* bo_l = boc + l * DD;
    const u16* W1_l = W1c + (size_t)l * 64 * DD; const u16* b1_l = b1c + l * 64;
    const u16* W2_l = W2c + (size_t)l * DD * 64; const u16* b2_l = b2c + l * DD;

    // fused QKV: grid (200, 12), block-uniform sel by n0>>9   [TAG 1]
    { GemmW g{}; g.W[0] = Wq_l; g.W[1] = Wk_l; g.W[2] = Wv_l;
      g.bias[0] = bq_l; g.bias[1] = bk_l; g.bias[2] = bv_l;
      g.out[0] = qb; g.out[1] = kb; g.out[2] = vb;
      gemm_bt<128, 1, true, false><<<dim3(MM / 128, 12), blk, 0, stream>>>(hbf, DD, g, nullptr, nullptr, 0, 0, DD, DD, nullptr); }

    attn<<<dim3(BB * HH), blk, 0, stream>>>(qb, kb, vb, ob);

    // h += o @ Wo^T + bo   [TAG 2]
    { GemmW g = W1of(Wo_l); g.bias[0] = g.bias[1] = g.bias[2] = bo_l; g.out[0] = g.out[1] = g.out[2] = hbf;
      gemm_bt<128, 2, false, false><<<dim3(MM / 128, 4), blk, 0, stream>>>(ob, DD, g, nullptr, h32, 1, 0, DD, DD, nullptr); }
    // y = gelu(h @ W1^T + b1)   [TAG 3]
    { GemmW g = W1of(W1_l); g.bias[0] = b1_l; g.out[0] = yb;
      gemm_bt<64, 3, false, false><<<dim3(MM / 128, 1), blk, 0, stream>>>(hbf, DD, g, nullptr, nullptr, 0, 1, 64, 64, nullptr); }
    // h += y @ W2^T + b2   [TAG 4]
    { GemmW g = W1of(W2_l); g.bias[0] = g.bias[1] = g.bias[2] = b2_l; g.out[0] = g.out[1] = g.out[2] = hbf;
      gemm_bt<128, 4, false, false><<<dim3(MM / 128, 4), blk, 0, stream>>>(yb, 64, g, nullptr, h32, 1, 0, DD, DD, nullptr); }
  }
  // out = h @ proj_w^T + proj_b (N=55, direct masked stores; dtype per flag)   [TAG 5]
  { GemmW g = W1of(pwc); g.bias[0] = pbc; g.out[0] = d_out;
    gemm_bt<64, 5, false, true><<<dim3(MM / 128, 1), blk, 0, stream>>>(hbf, DD, g, nullptr, nullptr, 0, 0, CC, CC, dflag); }
}

// Round 5
// 858.603 us; speedup vs baseline: 1.3157x; 1.3157x over previous
//
#include <hip/hip_runtime.h>
#include <stdint.h>

typedef unsigned short u16;
typedef __attribute__((ext_vector_type(8))) short short8;
typedef __attribute__((ext_vector_type(4))) float f32x4;

#define DEVI __device__ __forceinline__

// problem constants
#define BB   256
#define LL   100
#define CC   55
#define DD   512
#define HH   8
#define DKK  64
#define MM   (BB * LL)   // 25600 tokens
#define KEMB 192         // 3 * 64 (c padded 55->64)
#define NSEG 17

DEVI float bf2f(u16 s) { union { unsigned int u; float f; } x; x.u = ((unsigned int)s) << 16; return x.f; }
DEVI u16 f2bf(float f) {
  union { float f; unsigned int u; } x; x.f = f;
  unsigned int u = x.u;
  return (u16)((u + 0x7FFFu + ((u >> 16) & 1u)) >> 16);
}

DEVI void async_lds16(const u16* gp, u16* lp) {
  __builtin_amdgcn_global_load_lds((const __attribute__((address_space(1))) void*)gp,
                                   (__attribute__((address_space(3))) void*)lp, 16, 0, 0);
}

DEVI void wave_lds_fence() {   // wave-local LDS RAW/WAR fence (no cross-wave sync)
  asm volatile("s_waitcnt lgkmcnt(0)" ::: "memory");
  __builtin_amdgcn_wave_barrier();
}

// ---------------- dtype detect + canonicalize ----------------
__global__ void detect_dtype(const u16* __restrict__ x, int* __restrict__ flag) {
  __shared__ int cnt[256];
  int tid = threadIdx.x;
  u16 u = x[2 * tid];
  int e = (u >> 7) & 0xFF;
  cnt[tid] = (e >= 0x5F && e <= 0x90) ? 1 : 0;   // |v| in [2^-32, 2^17]
  __syncthreads();
  for (int s = 128; s > 0; s >>= 1) { if (tid < s) cnt[tid] += cnt[tid + s]; __syncthreads(); }
  if (tid == 0) *flag = (cnt[0] >= 160) ? 0 : 1;
}

struct Segs { const void* src[NSEG]; int off[NSEG + 1]; };

__global__ void convert_all(Segs s, const int* __restrict__ flag, u16* __restrict__ dst) {
  int i = blockIdx.x * 256 + threadIdx.x;
  if (i >= s.off[NSEG]) return;
  int sidx = 0;
#pragma unroll
  for (int k = 1; k < NSEG; k++) if (i >= s.off[k]) sidx = k;
  int j = i - s.off[sidx];
  u16 v;
  if (*flag) v = f2bf(((const float*)s.src[sidx])[j]);
  else       v = ((const u16*)s.src[sidx])[j];
  dst[i] = v;
}

// ---------------- repack kernels (embedding conv -> GEMM) ----------------
__global__ void repack_w(const u16* __restrict__ tokw, u16* __restrict__ Wg) {
  int idx = blockIdx.x * 256 + threadIdx.x;   // 512*192
  if (idx >= 512 * KEMB) return;
  int d = idx / KEMB, j = idx % KEMB, k = j >> 6, c = j & 63;
  Wg[idx] = (c < CC) ? tokw[d * (CC * 3) + c * 3 + k] : (u16)0;
}

__global__ void repack_x(const u16* __restrict__ x, u16* __restrict__ Xg) {
  int idx = blockIdx.x * 256 + threadIdx.x;   // 25600*192
  if (idx >= MM * KEMB) return;
  int m = idx / KEMB, j = idx % KEMB, k = j >> 6, c = j & 63;
  int b = m / LL, l = m % LL;
  int l2 = l + k - 1; l2 = (l2 + LL) % LL;    // circular pad
  Xg[idx] = (c < CC) ? x[(size_t)(b * LL + l2) * CC + c] : (u16)0;
}

// ---------------- bf16 MFMA GEMM: out = A[M,K] @ W[N,K]^T (+epilogue) ----------------
// BK=32 (verified-free LDS banking, m97 pattern). 256 threads = 4 waves as 2x2.
// QKV: grid.y spans 3 concatenated weight sets (block-uniform sel by n0>>9).
// Epilogue: bias/pe/master fp32 R/W DIRECT in C-fragment layout (quad-coalesced
// 64B dword segments); bf16 tile store via per-wave-exclusive 16-row LDS slab
// (wave-local waitcnt fences, no extra __syncthreads) -> full-line bf16x8 stores.
struct GemmW { const u16* W[3]; const u16* bias[3]; void* out[3]; };

template<int BM, int BN, int TAG, bool QKV, bool DIRECT>
__global__ __launch_bounds__(256)
void gemm_bt(const u16* __restrict__ A, int K, GemmW w,
             const u16* __restrict__ pe,     // if non-null: add pe[(m%100)*512+col]
             float* __restrict__ master,     // if non-null: (addm? +=) write fp32 master [M,512]
             int addm, int dogelu,
             int ldo, int nvalid,
             const int* __restrict__ dtf)    // DIRECT only: *dtf==1 -> fp32 store
{
  constexpr int BK = 32;
  constexpr int MI = BM / 32;                 // 16-row tiles per wave (rows = BM/2 per wave)
  constexpr int CW = BN / 2, NT = CW / 16;    // cols per wave
  constexpr int SW = CW + 4;                  // slab stride (u16)
  constexpr int STAGE_U16 = (BM + BN) * BK;
  __shared__ alignas(16) u16 smem[STAGE_U16];
  u16* As = smem;
  u16* Bs = smem + BM * BK;

  const int tid = threadIdx.x;
  const int lane = tid & 63;
  const int wv = __builtin_amdgcn_readfirstlane(tid >> 6);
  const int wm = wv & 1, wn = wv >> 1;
  const int l15 = lane & 15, qd = lane >> 4;
  const int m0 = blockIdx.x * BM;
  int n0 = blockIdx.y * BN;
  int sel = 0, n0l = n0;
  if (QKV) { sel = n0 >> 9; n0l = n0 & 511; }
  const u16* W = w.W[sel];
  const u16* bias = w.bias[sel];
  void* outp = w.out[sel];

  const f32x4 zf = {0.f, 0.f, 0.f, 0.f};
  f32x4 acc[MI][NT];
#pragma unroll
  for (int i = 0; i < MI; i++)
#pragma unroll
    for (int j = 0; j < NT; j++) acc[i][j] = zf;

  for (int k0 = 0; k0 < K; k0 += BK) {
    __syncthreads();
#pragma unroll
    for (int i = 0; i < BM / 64; i++) {               // A tile: BMx32, 16B chunks
      int base = i * 256 + wv * 64;
      int idx = base + lane;
      int row = idx >> 2, c8 = (idx & 3) * 8;
      async_lds16(A + (size_t)(m0 + row) * K + k0 + c8, As + base * 8);
    }
#pragma unroll
    for (int i = 0; i < BN / 64; i++) {               // B rows, clamped tail
      int base = i * 256 + wv * 64;
      int idx = base + lane;
      int row = idx >> 2, c8 = (idx & 3) * 8;
      int gr = n0l + row; if (gr >= nvalid) gr = nvalid - 1;
      async_lds16(W + (size_t)gr * K + k0 + c8, Bs + base * 8);
    }
    __syncthreads();

    short8 af[MI], bfr[NT];
#pragma unroll
    for (int mi = 0; mi < MI; mi++)
      af[mi] = *(const short8*)&As[(wm * (BM / 2) + mi * 16 + l15) * BK + qd * 8];
#pragma unroll
    for (int ni = 0; ni < NT; ni++)
      bfr[ni] = *(const short8*)&Bs[(wn * CW + ni * 16 + l15) * BK + qd * 8];
#pragma unroll
    for (int mi = 0; mi < MI; mi++)
#pragma unroll
      for (int ni = 0; ni < NT; ni++)
        acc[mi][ni] = __builtin_amdgcn_mfma_f32_16x16x32_bf16(af[mi], bfr[ni], acc[mi][ni], 0, 0, 0);
  }

  // C/D layout: col=lane&15, row=(lane>>4)*4+reg [verified m89/m91]
  if (DIRECT) {
    const int sf = (dtf != nullptr) ? *dtf : 0;
#pragma unroll
    for (int mi = 0; mi < MI; mi++)
#pragma unroll
      for (int ni = 0; ni < NT; ni++) {
        int gcol = n0l + wn * CW + ni * 16 + l15;
        float bv = (bias && gcol < nvalid) ? bf2f(bias[gcol]) : 0.f;
#pragma unroll
        for (int r = 0; r < 4; r++) {
          int grow = m0 + wm * (BM / 2) + mi * 16 + qd * 4 + r;
          if (gcol < nvalid) {
            float v = acc[mi][ni][r] + bv;
            if (sf) ((float*)outp)[(size_t)grow * ldo + gcol] = v;
            else    ((u16*)outp)[(size_t)grow * ldo + gcol] = f2bf(v);
          }
        }
      }
    return;
  }

  __syncthreads();                                    // retire staging reads; reuse smem
  u16* slab = smem + wv * 16 * SW;                    // per-wave exclusive, 16 rows
#pragma unroll
  for (int mi = 0; mi < MI; mi++) {
    const int lr = wm * (BM / 2) + mi * 16 + qd * 4;  // local row base (frag layout)
    float v[NT][4];
    // batched master fp32 loads (quad-coalesced 64B segments)
    if (!QKV && master && addm) {
#pragma unroll
      for (int ni = 0; ni < NT; ni++) {
        int col = n0l + wn * CW + ni * 16 + l15;
#pragma unroll
        for (int r = 0; r < 4; r++)
          v[ni][r] = master[(size_t)(m0 + lr + r) * DD + col];
      }
    } else {
#pragma unroll
      for (int ni = 0; ni < NT; ni++)
#pragma unroll
        for (int r = 0; r < 4; r++) v[ni][r] = 0.f;
    }
#pragma unroll
    for (int ni = 0; ni < NT; ni++) {
      const int lc = wn * CW + ni * 16 + l15;
      float bv = bias ? bf2f(bias[n0l + lc]) : 0.f;
#pragma unroll
      for (int r = 0; r < 4; r++) {
        float x = v[ni][r] + acc[mi][ni][r] + bv;
        if (!QKV && pe) x += bf2f(pe[((m0 + lr + r) % LL) * DD + n0l + lc]);
        if (!QKV && master) master[(size_t)(m0 + lr + r) * DD + n0l + lc] = x;
        if (!QKV && dogelu) x = 0.5f * x * (1.f + erff(x * 0.70710678118654752f));
        v[ni][r] = x;
      }
    }
    // bf16 out via wave-local slab transpose -> full-line stores
#pragma unroll
    for (int ni = 0; ni < NT; ni++)
#pragma unroll
      for (int r = 0; r < 4; r++)
        slab[(qd * 4 + r) * SW + ni * 16 + l15] = f2bf(v[ni][r]);
    wave_lds_fence();
    if (BN == 128) {                                  // 4 lanes x 32B per row = 128B lines
      int r2 = lane >> 2, c2 = (lane & 3) * 16;
      int grow = m0 + wm * (BM / 2) + mi * 16 + r2;
      u16* op = (u16*)outp + (size_t)grow * ldo + n0l + wn * CW + c2;
      *(short8*)&op[0] = *(const short8*)&slab[r2 * SW + c2];
      *(short8*)&op[8] = *(const short8*)&slab[r2 * SW + c2 + 8];
    } else {                                          // BN=64: 2 lanes x 32B per row
      if (lane < 32) {
        int r2 = lane >> 1, c2 = (lane & 1) * 16;
        int grow = m0 + wm * (BM / 2) + mi * 16 + r2;
        u16* op = (u16*)outp + (size_t)grow * ldo + n0l + wn * CW + c2;
        *(short8*)&op[0] = *(const short8*)&slab[r2 * SW + c2];
        *(short8*)&op[8] = *(const short8*)&slab[r2 * SW + c2 + 8];
      }
    }
    wave_lds_fence();                                 // WAR guard before next mi
  }
}

// ---------------- fused attention: one block per (b,h) ----------------
__global__ __launch_bounds__(256)
void attn(const u16* __restrict__ qg, const u16* __restrict__ kg,
          const u16* __restrict__ vg, u16* __restrict__ og)
{
  constexpr int LP = 128;
  __shared__ alignas(16) u16 Ks[LP * DKK];   // 16 KB
  __shared__ alignas(16) u16 Vt[DKK * LP];   // 16 KB  V transposed [d][j]
  __shared__ alignas(16) u16 Ps[LP * LP];    // 32 KB  probs; reused for O staging

  const int bh = blockIdx.x;
  const int b = bh >> 3, h = bh & 7;
  const size_t base = (size_t)b * LL * DD + (size_t)h * DKK;
  const int tid = threadIdx.x, lane = tid & 63, wv = tid >> 6;
  const int l15 = lane & 15, qd = lane >> 4;
  const short8 z8 = {0, 0, 0, 0, 0, 0, 0, 0};

  for (int i = tid; i < LP * 8; i += 256) {            // K rows, zero-padded
    int row = i >> 3, e8 = (i & 7) * 8;
    short8 val = z8;
    if (row < LL) val = *(const short8*)(kg + base + (size_t)row * DD + e8);
    *(short8*)&Ks[row * DKK + e8] = val;
  }
  for (int i = tid; i < LP * 8; i += 256) {            // V transposed
    int j = i & 127, d0 = (i >> 7) * 8;
    short8 val = z8;
    if (j < LL) val = *(const short8*)(vg + base + (size_t)j * DD + d0);
#pragma unroll
    for (int u = 0; u < 8; u++) Vt[(d0 + u) * LP + j] = (u16)val[u];
  }
  __syncthreads();

  const f32x4 zf = {0.f, 0.f, 0.f, 0.f};
  f32x4 sc[2][8];
#pragma unroll
  for (int it = 0; it < 2; it++)
#pragma unroll
    for (int jt = 0; jt < 8; jt++) sc[it][jt] = zf;

  short8 af[2][2];
#pragma unroll
  for (int it = 0; it < 2; it++) {
    int row = (2 * wv + it) * 16 + l15;
#pragma unroll
    for (int ks = 0; ks < 2; ks++) {
      short8 val = z8;
      if (row < LL) val = *(const short8*)(qg + base + (size_t)row * DD + ks * 32 + qd * 8);
      af[it][ks] = val;
    }
  }
#pragma unroll
  for (int jt = 0; jt < 8; jt++) {
    short8 b0 = *(const short8*)&Ks[(jt * 16 + l15) * DKK + qd * 8];
    short8 b1 = *(const short8*)&Ks[(jt * 16 + l15) * DKK + 32 + qd * 8];
#pragma unroll
    for (int it = 0; it < 2; it++) {
      sc[it][jt] = __builtin_amdgcn_mfma_f32_16x16x32_bf16(af[it][0], b0, sc[it][jt], 0, 0, 0);
      sc[it][jt] = __builtin_amdgcn_mfma_f32_16x16x32_bf16(af[it][1], b1, sc[it][jt], 0, 0, 0);
    }
  }

  constexpr float scale = 0.125f;   // 1/sqrt(64)
#pragma unroll
  for (int it = 0; it < 2; it++) {
    int rb = (2 * wv + it) * 16 + qd * 4;
#pragma unroll
    for (int r = 0; r < 4; r++) {
      float vals[8];
      float mx = -1e30f;
#pragma unroll
      for (int jt = 0; jt < 8; jt++) {
        int col = jt * 16 + l15;
        float vv = sc[it][jt][r] * scale;
        if (col >= LL) vv = -1e30f;
        vals[jt] = vv;
        mx = fmaxf(mx, vv);
      }
#pragma unroll
      for (int off = 1; off < 16; off <<= 1) mx = fmaxf(mx, __shfl_xor(mx, off, 64));
      float s = 0.f;
#pragma unroll
      for (int jt = 0; jt < 8; jt++) { float p = __expf(vals[jt] - mx); vals[jt] = p; s += p; }
#pragma unroll
      for (int off = 1; off < 16; off <<= 1) s += __shfl_xor(s, off, 64);
      float inv = 1.f / s;
      int rowp = rb + r;
#pragma unroll
      for (int jt = 0; jt < 8; jt++) Ps[rowp * LP + jt * 16 + l15] = f2bf(vals[jt] * inv);
    }
  }
  __syncthreads();

  f32x4 oc[2][4];
#pragma unroll
  for (int it = 0; it < 2; it++)
#pragma unroll
    for (int dt = 0; dt < 4; dt++) oc[it][dt] = zf;
#pragma unroll
  for (int ks = 0; ks < 4; ks++) {
    short8 ap[2];
#pragma unroll
    for (int it = 0; it < 2; it++)
      ap[it] = *(const short8*)&Ps[((2 * wv + it) * 16 + l15) * LP + ks * 32 + qd * 8];
#pragma unroll
    for (int dt = 0; dt < 4; dt++) {
      short8 bv = *(const short8*)&Vt[(dt * 16 + l15) * LP + ks * 32 + qd * 8];
#pragma unroll
      for (int it = 0; it < 2; it++)
        oc[it][dt] = __builtin_amdgcn_mfma_f32_16x16x32_bf16(ap[it], bv, oc[it][dt], 0, 0, 0);
    }
  }

  // O staging -> vectorized store (reuse Ps as [128][64] bf16)
  __syncthreads();
  u16* Os = Ps;
#pragma unroll
  for (int it = 0; it < 2; it++) {
    int rb = (2 * wv + it) * 16 + qd * 4;
#pragma unroll
    for (int dt = 0; dt < 4; dt++)
#pragma unroll
      for (int r = 0; r < 4; r++)
        Os[(rb + r) * DKK + dt * 16 + l15] = f2bf(oc[it][dt][r]);
  }
  __syncthreads();
  {
    int row = tid >> 1, c0 = (tid & 1) * 32;
    if (row < LL) {
      u16* op = og + base + (size_t)row * DD + c0;
#pragma unroll
      for (int c = 0; c < 32; c += 8)
        *(short8*)&op[c] = *(const short8*)&Os[row * DKK + c0 + c];
    }
  }
}

// ---------------- launch ----------------
extern "C" void kernel_launch(void* const* d_in, const int* in_sizes, int n_in,
                              void* d_out, int out_size, void* d_ws, size_t ws_size,
                              hipStream_t stream)
{
  (void)in_sizes; (void)n_in; (void)out_size; (void)ws_size;

  char* ws = (char*)d_ws;
  size_t off = 0;
  auto alloc = [&](size_t bytes) { char* p = ws + off; off += (bytes + 255) & ~(size_t)255; return p; };
  int* dflag = (int*)alloc(256);
  static const int seg_sizes[NSEG] = {
    MM * CC, DD * CC * 3, LL * DD,
    3 * DD * DD, 3 * DD, 3 * DD * DD, 3 * DD, 3 * DD * DD, 3 * DD,
    3 * DD * DD, 3 * DD, 3 * 64 * DD, 3 * 64, 3 * DD * 64, 3 * DD,
    CC * DD, CC
  };
  static const int seg_input[NSEG] = {0, 1, 2, 3, 4, 5, 6, 7, 8, 11, 12, 13, 14, 15, 16, 17, 18};
  int total = 0, segoff[NSEG + 1];
  for (int i = 0; i < NSEG; i++) { segoff[i] = total; total += seg_sizes[i]; }
  segoff[NSEG] = total;
  u16* canon = (u16*)alloc((size_t)total * 2);

  float* h32 = (float*)alloc((size_t)MM * DD * 4);
  u16* hbf = (u16*)alloc((size_t)MM * DD * 2);
  u16* qb  = (u16*)alloc((size_t)MM * DD * 2);
  u16* kb  = (u16*)alloc((size_t)MM * DD * 2);
  u16* vb  = (u16*)alloc((size_t)MM * DD * 2);
  u16* ob  = (u16*)alloc((size_t)MM * DD * 2);
  u16* yb  = (u16*)alloc((size_t)MM * 64 * 2);
  u16* Wg  = (u16*)alloc((size_t)512 * KEMB * 2);
  u16* Xg  = qb;   // alias: Xg dead before qb first written (stream-serialized)

  const u16* xc  = canon + segoff[0];
  const u16* twc = canon + segoff[1];
  const u16* pec = canon + segoff[2];
  const u16* Wqc = canon + segoff[3];  const u16* bqc = canon + segoff[4];
  const u16* Wkc = canon + segoff[5];  const u16* bkc = canon + segoff[6];
  const u16* Wvc = canon + segoff[7];  const u16* bvc = canon + segoff[8];
  const u16* Woc = canon + segoff[9];  const u16* boc = canon + segoff[10];
  const u16* W1c = canon + segoff[11]; const u16* b1c = canon + segoff[12];
  const u16* W2c = canon + segoff[13]; const u16* b2c = canon + segoff[14];
  const u16* pwc = canon + segoff[15]; const u16* pbc = canon + segoff[16];

  Segs sg;
  for (int i = 0; i < NSEG; i++) { sg.src[i] = d_in[seg_input[i]]; sg.off[i] = segoff[i]; }
  sg.off[NSEG] = total;

  dim3 blk(256);
  detect_dtype<<<dim3(1), blk, 0, stream>>>((const u16*)d_in[0], dflag);
  convert_all<<<dim3((total + 255) / 256), blk, 0, stream>>>(sg, dflag, canon);
  repack_w<<<dim3((512 * KEMB + 255) / 256), blk, 0, stream>>>(twc, Wg);
  repack_x<<<dim3((MM * KEMB + 255) / 256), blk, 0, stream>>>(xc, Xg);

  auto W1of = [&](const u16* p) { GemmW g{}; g.W[0] = g.W[1] = g.W[2] = p; return g; };

  // embedding GEMM: h = Xg @ Wg^T + pe -> h32 (write), hbf   [TAG 0]
  { GemmW g = W1of(Wg); g.out[0] = hbf;
    gemm_bt<128, 128, 0, false, false><<<dim3(MM / 128, 4), blk, 0, stream>>>(Xg, KEMB, g, pec, h32, 0, 0, DD, DD, nullptr); }

  for (int l = 0; l < 3; l++) {
    const u16* Wq_l = Wqc + (size_t)l * DD * DD; const u16* bq_l = bqc + l * DD;
    const u16* Wk_l = Wkc + (size_t)l * DD * DD; const u16* bk_l = bkc + l * DD;
    const u16* Wv_l = Wvc + (size_t)l * DD * DD; const u16* bv_l = bvc + l * DD;
    const u16* Wo_l = Woc + (size_t)l * DD * DD; const u16* bo_l = boc + l * DD;
    const u16* W1_l = W1c + (size_t)l * 64 * DD; const u16* b1_l = b1c + l * 64;
    const u16* W2_l = W2c + (size_t)l * DD * 64; const u16* b2_l = b2c + l * DD;

    // fused QKV: grid (200, 12), block-uniform sel by n0>>9   [TAG 1]
    { GemmW g{}; g.W[0] = Wq_l; g.W[1] = Wk_l; g.W[2] = Wv_l;
      g.bias[0] = bq_l; g.bias[1] = bk_l; g.bias[2] = bv_l;
      g.out[0] = qb; g.out[1] = kb; g.out[2] = vb;
      gemm_bt<128, 128, 1, true, false><<<dim3(MM / 128, 12), blk, 0, stream>>>(hbf, DD, g, nullptr, nullptr, 0, 0, DD, DD, nullptr); }

    attn<<<dim3(BB * HH), blk, 0, stream>>>(qb, kb, vb, ob);

    // h += o @ Wo^T + bo   [TAG 2]
    { GemmW g = W1of(Wo_l); g.bias[0] = g.bias[1] = g.bias[2] = bo_l; g.out[0] = g.out[1] = g.out[2] = hbf;
      gemm_bt<128, 128, 2, false, false><<<dim3(MM / 128, 4), blk, 0, stream>>>(ob, DD, g, nullptr, h32, 1, 0, DD, DD, nullptr); }
    // y = gelu(h @ W1^T + b1)   [TAG 3]
    { GemmW g = W1of(W1_l); g.bias[0] = b1_l; g.out[0] = yb;
      gemm_bt<64, 64, 3, false, false><<<dim3(MM / 64, 1), blk, 0, stream>>>(hbf, DD, g, nullptr, nullptr, 0, 1, 64, 64, nullptr); }
    // h += y @ W2^T + b2   [TAG 4]
    { GemmW g = W1of(W2_l); g.bias[0] = g.bias[1] = g.bias[2] = b2_l; g.out[0] = g.out[1] = g.out[2] = hbf;
      gemm_bt<128, 128, 4, false, false><<<dim3(MM / 128, 4), blk, 0, stream>>>(yb, 64, g, nullptr, h32, 1, 0, DD, DD, nullptr); }
  }
  // out = h @ proj_w^T + proj_b (N=55, direct masked stores; dtype per flag)   [TAG 5]
  { GemmW g = W1of(pwc); g.bias[0] = pbc; g.out[0] = d_out;
    gemm_bt<64, 64, 5, false, true><<<dim3(MM / 64, 1), blk, 0, stream>>>(hbf, DD, g, nullptr, nullptr, 0, 0, CC, CC, dflag); }
}